// Round 6
// baseline (174.821 us; speedup 1.0000x reference)
//
#include <hip/hip_runtime.h>
#include <hip/hip_bf16.h>

// B=8, H=W=32 (seq=1024), C=512, heads=8, head_dim=64, groups=32
#define SEQ   1024
#define CH    512
#define NHEAD 8
#define HDIM  64
#define BATCH 8

using short8  = __attribute__((ext_vector_type(8))) short;
using floatx4 = __attribute__((ext_vector_type(4))) float;
using uint4v  = __attribute__((ext_vector_type(4))) unsigned int;

#if __has_builtin(__builtin_amdgcn_exp2f)
#define EXP2F __builtin_amdgcn_exp2f
#else
#define EXP2F exp2f
#endif

__device__ inline unsigned short f2bf(float f) {
  __hip_bfloat16 h = __float2bfloat16(f);
  return __builtin_bit_cast(unsigned short, h);
}

// packed f32x2 -> bf16x2 (RNE), single VALU inst; low half = first arg
__device__ inline unsigned int cvt_pk_bf16(float lo, float hi) {
  unsigned int r;
  asm("v_cvt_pk_bf16_f32 %0, %1, %2" : "=v"(r) : "v"(lo), "v"(hi));
  return r;
}

// async 16B global->LDS DMA (lane-linear LDS dest required)
__device__ inline void load_lds16(const void* g, void* l) {
  __builtin_amdgcn_global_load_lds(
      (const __attribute__((address_space(1))) unsigned int*)g,
      (__attribute__((address_space(3))) unsigned int*)l, 16, 0, 0);
}

// ---------------------------------------------------------------------------
// K1 (fused): blocks 0..255 = GroupNorm for one (b,g).  Each thread's 16
// values (4x float4) are held in REGISTERS across the stats reduction --
// no 64KB LDS round-trip.  LDS is only the 17KB transpose tile + scratch.
// Blocks 256..447: wqkv transpose (64x64 tiles); 448..511: wout transpose.
// ---------------------------------------------------------------------------
__global__ __launch_bounds__(1024) void prep_kernel(
    const float* __restrict__ wqkv, const float* __restrict__ wout,
    const float* __restrict__ x, const float* __restrict__ gsc,
    const float* __restrict__ gbs,
    unsigned short* __restrict__ wqkvt, unsigned short* __restrict__ woutt,
    unsigned short* __restrict__ xn) {
  __shared__ float SH[64 * 65 + 32];   // transpose tile + reduce scratch
  const int blk = blockIdx.x, tid = threadIdx.x;

  if (blk >= 256) {
    // ---- weight transpose, 64x64 tile, bf16 out ----
    const float* src; unsigned short* dst; int C, bx, by;
    if (blk < 448) { int t = blk - 256; src = wqkv; dst = wqkvt; C = 1536; bx = t % 24; by = t / 24; }
    else           { int t = blk - 448; src = wout; dst = woutt; C = 512;  bx = t & 7;  by = t >> 3; }
    float (*T)[65] = (float(*)[65])SH;
    int tx = tid & 63, ty = tid >> 6;            // ty 0..15
    for (int j = 0; j < 4; ++j)
      T[ty + j * 16][tx] = src[(size_t)(by * 64 + ty + j * 16) * C + bx * 64 + tx];
    __syncthreads();
    for (int j = 0; j < 4; ++j)
      dst[(size_t)(bx * 64 + ty + j * 16) * 512 + by * 64 + tx] = f2bf(T[tx][ty + j * 16]);
    return;
  }

  // ---- GroupNorm, one (b,g) per block; tile kept in registers ----
  const int b = blk >> 5, g = blk & 31;
  const size_t base = (size_t)b * SEQ * CH + g * 16;

  float4 v[4];
  float s = 0.f, sq = 0.f;
  for (int i = 0; i < 4; ++i) {
    int c = (i << 10) + tid;                     // 4096 float4 chunks
    int r = c >> 2, c4 = (c & 3) << 2;
    v[i] = *(const float4*)(x + base + (size_t)r * CH + c4);
    s  += v[i].x + v[i].y + v[i].z + v[i].w;
    sq += v[i].x * v[i].x + v[i].y * v[i].y + v[i].z * v[i].z + v[i].w * v[i].w;
  }
  for (int off = 1; off < 64; off <<= 1) {
    s  += __shfl_xor(s, off);
    sq += __shfl_xor(sq, off);
  }
  const int wid = tid >> 6, lane = tid & 63;
  float* scr = SH + 64 * 65;
  if (lane == 0) { scr[wid] = s; scr[16 + wid] = sq; }
  __syncthreads();
  float ts = 0.f, tq = 0.f;
  for (int i = 0; i < 16; ++i) { ts += scr[i]; tq += scr[16 + i]; }
  const float inv_n = 1.0f / 16384.0f;
  float mean = ts * inv_n;
  float var  = tq * inv_n - mean * mean;
  float rstd = rsqrtf(var + 1e-6f);

  int c4 = (tid & 3) << 2;
  float4 sc = *(const float4*)(gsc + g * 16 + c4);
  float4 bs = *(const float4*)(gbs + g * 16 + c4);
  for (int i = 0; i < 4; ++i) {
    int c = (i << 10) + tid;
    int r = c >> 2;
    ushort4 o;
    o.x = f2bf((v[i].x - mean) * rstd * sc.x + bs.x);
    o.y = f2bf((v[i].y - mean) * rstd * sc.y + bs.y);
    o.z = f2bf((v[i].z - mean) * rstd * sc.z + bs.z);
    o.w = f2bf((v[i].w - mean) * rstd * sc.w + bs.w);
    *(ushort4*)(xn + base + (size_t)r * CH + c4) = o;
  }
}

// ---------------------------------------------------------------------------
// K2/K4: GEMM C = A(MxK) * Bt(NxK)^T, bf16 in, fp32 acc, MTILE x 128 tile.
// Grid is (m-tile, n-tile) so blocks sharing an A-tile get the same
// linear%8 -> same XCD (L2 locality).  BK=64, global_load_lds staging,
// XOR-swizzled LDS.  Epilogues via LDS -> 16B global stores.
// EPI 0 (MTILE=128, QKV): +bias; q scaled (1/64)*log2e; q/k -> (h,s,d);
//     v -> transposed vt (h,d,s) with s permuted within 32-blocks so attn
//     PV P-frags form 16x16x32 A-operands with zero cross-lane ops.
// EPI 1 (MTILE=64, out):  +bias +residual, fp32 out.
// ---------------------------------------------------------------------------
template <int EPI, int MTILE>
__global__ __launch_bounds__(256) void gemm_bt_kernel(
    const unsigned short* __restrict__ A, const unsigned short* __restrict__ Bt,
    int K, int N,
    const float* __restrict__ bias, const float* __restrict__ resid,
    float* __restrict__ outf,
    unsigned short* __restrict__ qb, unsigned short* __restrict__ kb,
    unsigned short* __restrict__ vtb) {
  constexpr int SMSZ = (MTILE == 128) ? 17408 : 16896;
  constexpr int NI   = (MTILE == 128) ? 4 : 2;
  __shared__ alignas(16) unsigned short SM[SMSZ];
  unsigned short* LA = SM;                 // MTILE x 64, swizzled
  unsigned short* LB = SM + MTILE * 64;    // 128 x 64, swizzled

  const int tid = threadIdx.x;
  const int wid = tid >> 6, lane = tid & 63;
  const int quad = lane >> 4, m16 = lane & 15;
  const int sw = m16 & 7;
  const int wm = (MTILE == 128) ? (wid & 1) * 64 : 0;
  const int wn = (MTILE == 128) ? (wid >> 1) * 64 : wid * 32;
  const int m0 = blockIdx.x * MTILE, n0 = blockIdx.y * 128;

  floatx4 acc[4][NI];
  for (int i = 0; i < 4; ++i)
    for (int j = 0; j < NI; ++j) acc[i][j] = 0.f;

  for (int k0 = 0; k0 < K; k0 += 64) {
    for (int i = 0; i < MTILE / 32; ++i) {
      int c = i * 256 + tid;
      int r = c >> 3, kc = c & 7;
      load_lds16(A + (size_t)(m0 + r) * K + k0 + ((kc ^ (r & 7)) << 3), &LA[c << 3]);
    }
    for (int i = 0; i < 4; ++i) {
      int c = i * 256 + tid;
      int r = c >> 3, kc = c & 7;
      load_lds16(Bt + (size_t)(n0 + r) * K + k0 + ((kc ^ (r & 7)) << 3), &LB[c << 3]);
    }
    __syncthreads();
    for (int kq = 0; kq < 2; ++kq) {
      int csw = (((kq << 2) + quad) ^ sw) << 3;
      short8 af[4], bf[NI];
      for (int mi = 0; mi < 4; ++mi)
        af[mi] = *(const short8*)&LA[(wm + mi * 16 + m16) * 64 + csw];
      for (int ni = 0; ni < NI; ++ni)
        bf[ni] = *(const short8*)&LB[(wn + ni * 16 + m16) * 64 + csw];
      for (int mi = 0; mi < 4; ++mi)
        for (int ni = 0; ni < NI; ++ni)
          acc[mi][ni] = __builtin_amdgcn_mfma_f32_16x16x32_bf16(af[mi], bf[ni], acc[mi][ni], 0, 0, 0);
    }
    __syncthreads();
  }

  // C/D layout: row = quad*4+reg, col = lane&15
  const int b = m0 >> 10;
  if (EPI == 0) {
    const int part = n0 >> 9;                // 0=q 1=k 2=v (block-uniform)
    if (part < 2) {
      const float qscale = (part == 0) ? 0.0225421381f : 1.0f;  // (1/64)*log2e
      unsigned short* dst = (part == 0) ? qb : kb;
      for (int mi = 0; mi < 4; ++mi)
        for (int ni = 0; ni < 4; ++ni) {
          int ln = wn + ni * 16 + m16;
          float bb = bias[n0 + ln];
          for (int reg = 0; reg < 4; ++reg)
            SM[(wm + mi * 16 + quad * 4 + reg) * 136 + ln] =
                f2bf((acc[mi][ni][reg] + bb) * qscale);
        }
      __syncthreads();
      const int colb = n0 & 511;
      for (int j = 0; j < 8; ++j) {
        int c = j * 256 + tid;               // 2048 16B chunks
        int m = c >> 4, n8 = (c & 15) * 8;
        int h = (colb + n8) >> 6, d = n8 & 63;
        int sp = (m0 & 1023) + m;
        int4 v = *(const int4*)&SM[m * 136 + n8];
        *(int4*)(dst + (((size_t)(b * NHEAD + h)) * SEQ + sp) * HDIM + d) = v;
      }
    } else {
      // v: transpose [n][m], m permuted within 32-blocks (slot = 32*(mblk>>1)
      // + 8*quad + 4*(mblk&1) + reg) for attn's K=32 PV A-operands
      for (int mi = 0; mi < 4; ++mi)
        for (int ni = 0; ni < 4; ++ni) {
          int ln = wn + ni * 16 + m16;
          float bb = bias[n0 + ln];
          int mblk = (wm >> 4) + mi;
          int sbase = 32 * (mblk >> 1) + 8 * quad + 4 * (mblk & 1);
          for (int reg = 0; reg < 4; ++reg)
            SM[ln * 136 + sbase + reg] = f2bf(acc[mi][ni][reg] + bb);
        }
      __syncthreads();
      int hbase = (n0 - 1024) >> 6;
      for (int j = 0; j < 8; ++j) {
        int c = j * 256 + tid;
        int ld = c >> 4, sp8 = (c & 15) * 8;
        int h = hbase + (ld >> 6), d = ld & 63;
        int4 v = *(const int4*)&SM[ld * 136 + sp8];
        *(int4*)(vtb + ((size_t)(b * NHEAD + h) * HDIM + d) * SEQ + (m0 & 1023) + sp8) = v;
      }
    }
  } else {
    float* SMf = (float*)SM;                 // 64 x 132 fp32
    for (int mi = 0; mi < 4; ++mi)
      for (int ni = 0; ni < NI; ++ni) {
        int ln = wn + ni * 16 + m16;
        float bb = bias[n0 + ln];
        for (int reg = 0; reg < 4; ++reg)
          SMf[(mi * 16 + quad * 4 + reg) * 132 + ln] = acc[mi][ni][reg] + bb;
      }
    __syncthreads();
    for (int j = 0; j < 8; ++j) {
      int c = j * 256 + tid;                 // 2048 float4 chunks
      int m = c >> 5, n4 = (c & 31) * 4;
      size_t idx = (size_t)(m0 + m) * N + n0 + n4;
      float4 v = *(const float4*)&SMf[m * 132 + n4];
      float4 rr = *(const float4*)&resid[idx];
      v.x += rr.x; v.y += rr.y; v.z += rr.z; v.w += rr.w;
      *(float4*)&outf[idx] = v;
    }
  }
}

// ---------------------------------------------------------------------------
// K3: flash attention with T14 async-STAGE (global->reg->LDS, loads issued
// at compute start).  r5 POST-MORTEM: __launch_bounds__(256,4) capped VGPR
// at 128 -> the +32 staging regs spilled to scratch (93MB writes, 56us).
// Fix: (256,2) -- grid is 512 blocks = 2 blocks/CU (grid-limited), so the
// ,4 constraint bought nothing; 256-VGPR ceiling removes the spill and
// gives T14 its fair test.
// Keeps: 32 q-rows/wave, single 32KB buffer, raw v_exp_f32, packed
// cvt_pk_bf16, ones-column MFMA denominator, setprio, LDS-coalesced epilogue.
// ---------------------------------------------------------------------------
__global__ __launch_bounds__(256, 2) void attn_kernel(
    const unsigned short* __restrict__ qb, const unsigned short* __restrict__ kb,
    const unsigned short* __restrict__ vtb, unsigned short* __restrict__ ao) {
  const int head = blockIdx.x, qt = blockIdx.y;
  const int b = head >> 3, h = head & 7;
  const int tid = threadIdx.x;
  const int wid = tid >> 6, lane = tid & 63;
  const int quad = lane >> 4, m16 = lane & 15;
  const int sw = m16 & 7;

  __shared__ alignas(16) unsigned short SMEM[16384];   // 32 KB
  unsigned short* sK = SMEM;           // 128x64, swizzled (16 KB)
  unsigned short* sV = SMEM + 8192;    // Vt 64x128 (s permuted), swizzled (16 KB)

  const unsigned short* kbase = kb  + (size_t)head * SEQ * HDIM;
  const unsigned short* vbase = vtb + (size_t)head * HDIM * SEQ;

  // per-thread staging geometry (4 K-chunks + 4 V-chunks of 16B)
  int kr[4], kcs[4], vd[4], vcs[4];
  for (int i = 0; i < 4; ++i) {
    int c = i * 256 + tid;
    kr[i]  = c >> 3;
    kcs[i] = ((c & 7) ^ (kr[i] & 7)) << 3;
    vd[i]  = c >> 4;
    vcs[i] = ((c & 15) ^ (vd[i] & 7)) << 3;
  }

  // Q fragments for two 16-row q-blocks (pre-scaled by (1/64)*log2e upstream)
  short8 aq[2][2];
  for (int qblk = 0; qblk < 2; ++qblk) {
    const size_t qrow = (size_t)head * SEQ + qt * 128 + wid * 32 + qblk * 16 + m16;
    aq[qblk][0] = *(const short8*)(qb + qrow * HDIM + quad * 8);
    aq[qblk][1] = *(const short8*)(qb + qrow * HDIM + 32 + quad * 8);
  }

  const unsigned int onep = 0x3F803F80u;               // bf16(1.0) x2
  const short8 vones = __builtin_bit_cast(short8, (uint4v){onep, onep, onep, onep});

  floatx4 la[2];                                       // denominators, D-layout
  floatx4 o[2][4];
  for (int qblk = 0; qblk < 2; ++qblk) {
    la[qblk] = 0.f;
    for (int df = 0; df < 4; ++df) o[qblk][df] = 0.f;
  }

  // prologue: tile 0 global->reg->LDS
  int4 rk[4], rv[4];
  for (int i = 0; i < 4; ++i)
    rk[i] = *(const int4*)(kbase + (size_t)kr[i] * HDIM + kcs[i]);
  for (int i = 0; i < 4; ++i)
    rv[i] = *(const int4*)(vbase + (size_t)vd[i] * SEQ + vcs[i]);
  for (int i = 0; i < 4; ++i) *(int4*)&sK[(i * 256 + tid) << 3] = rk[i];
  for (int i = 0; i < 4; ++i) *(int4*)&sV[(i * 256 + tid) << 3] = rv[i];
  __syncthreads();

  for (int kt = 0; kt < 8; ++kt) {
    // T14: issue next tile's loads NOW; they land in regs during compute
    if (kt < 7) {
      const int kn = kt + 1;
      for (int i = 0; i < 4; ++i)
        rk[i] = *(const int4*)(kbase + (size_t)(kn * 128 + kr[i]) * HDIM + kcs[i]);
      for (int i = 0; i < 4; ++i)
        rv[i] = *(const int4*)(vbase + (size_t)vd[i] * SEQ + kn * 128 + vcs[i]);
    }

    // per-u: QK^T for the 2 sub-frags -> exp2 -> pack -> PV immediately.
    // sf=2u+t -> A-operand k=quad*8+4t+r.  pw live range = one u (8 VGPR).
    for (int u = 0; u < 4; ++u) {
      unsigned int pw[2][4];
      for (int t = 0; t < 2; ++t) {
        const int sf = u * 2 + t;
        const int rb = (sf * 16 + m16) * 64;
        short8 k0 = *(const short8*)&sK[rb + ((quad ^ sw) << 3)];
        short8 k1 = *(const short8*)&sK[rb + (((4 + quad) ^ sw) << 3)];
        floatx4 s0 = 0.f, s1 = 0.f;
        __builtin_amdgcn_s_setprio(1);
        s0 = __builtin_amdgcn_mfma_f32_16x16x32_bf16(k0, aq[0][0], s0, 0, 0, 0);
        s0 = __builtin_amdgcn_mfma_f32_16x16x32_bf16(k1, aq[0][1], s0, 0, 0, 0);
        s1 = __builtin_amdgcn_mfma_f32_16x16x32_bf16(k0, aq[1][0], s1, 0, 0, 0);
        s1 = __builtin_amdgcn_mfma_f32_16x16x32_bf16(k1, aq[1][1], s1, 0, 0, 0);
        __builtin_amdgcn_s_setprio(0);
        pw[0][t * 2 + 0] = cvt_pk_bf16(EXP2F(s0[0]), EXP2F(s0[1]));
        pw[0][t * 2 + 1] = cvt_pk_bf16(EXP2F(s0[2]), EXP2F(s0[3]));
        pw[1][t * 2 + 0] = cvt_pk_bf16(EXP2F(s1[0]), EXP2F(s1[1]));
        pw[1][t * 2 + 1] = cvt_pk_bf16(EXP2F(s1[2]), EXP2F(s1[3]));
      }
      const short8 pf0 = __builtin_bit_cast(
          short8, (uint4v){pw[0][0], pw[0][1], pw[0][2], pw[0][3]});
      const short8 pf1 = __builtin_bit_cast(
          short8, (uint4v){pw[1][0], pw[1][1], pw[1][2], pw[1][3]});
      const int chunk = ((u * 4 + quad) ^ sw) << 3;
      __builtin_amdgcn_s_setprio(1);
      for (int df = 0; df < 4; ++df) {
        short8 bv = *(const short8*)&sV[(df * 16 + m16) * 128 + chunk];
        o[0][df] = __builtin_amdgcn_mfma_f32_16x16x32_bf16(pf0, bv, o[0][df], 0, 0, 0);
        o[1][df] = __builtin_amdgcn_mfma_f32_16x16x32_bf16(pf1, bv, o[1][df], 0, 0, 0);
      }
      la[0] = __builtin_amdgcn_mfma_f32_16x16x32_bf16(pf0, vones, la[0], 0, 0, 0);
      la[1] = __builtin_amdgcn_mfma_f32_16x16x32_bf16(pf1, vones, la[1], 0, 0, 0);
      __builtin_amdgcn_s_setprio(0);
    }
    __syncthreads();                   // all waves done reading this tile
    if (kt < 7) {
      for (int i = 0; i < 4; ++i) *(int4*)&sK[(i * 256 + tid) << 3] = rk[i];
      for (int i = 0; i < 4; ++i) *(int4*)&sV[(i * 256 + tid) << 3] = rv[i];
      __syncthreads();                 // new tile visible
    }
  }

  // normalize into f32 scratch [128][64] (exactly 32KB), then coalesced write
  float* Sc = (float*)SMEM;
  for (int qblk = 0; qblk < 2; ++qblk) {
    floatx4 lr;
    for (int r = 0; r < 4; ++r) lr[r] = 1.0f / la[qblk][r];
    const int row0 = wid * 32 + qblk * 16 + quad * 4;
    for (int df = 0; df < 4; ++df) {
      const int col = df * 16 + m16;
      Sc[(row0 + 0) * 64 + col] = o[qblk][df][0] * lr[0];
      Sc[(row0 + 1) * 64 + col] = o[qblk][df][1] * lr[1];
      Sc[(row0 + 2) * 64 + col] = o[qblk][df][2] * lr[2];
      Sc[(row0 + 3) * 64 + col] = o[qblk][df][3] * lr[3];
    }
  }
  __syncthreads();
  for (int j = 0; j < 4; ++j) {
    int c = j * 256 + tid;             // 1024 8-col chunks
    int m = c >> 3, n8 = (c & 7) * 8;
    floatx4 v0 = *(const floatx4*)&Sc[m * 64 + n8];
    floatx4 v1 = *(const floatx4*)&Sc[m * 64 + n8 + 4];
    int4 w;
    w.x = (int)cvt_pk_bf16(v0[0], v0[1]);
    w.y = (int)cvt_pk_bf16(v0[2], v0[3]);
    w.z = (int)cvt_pk_bf16(v1[0], v1[1]);
    w.w = (int)cvt_pk_bf16(v1[2], v1[3]);
    *(int4*)(ao + (size_t)(b * SEQ + qt * 128 + m) * CH + h * HDIM + n8) = w;
  }
}

// ---------------------------------------------------------------------------
extern "C" void kernel_launch(void* const* d_in, const int* in_sizes, int n_in,
                              void* d_out, int out_size, void* d_ws, size_t ws_size,
                              hipStream_t stream) {
  const float* x    = (const float*)d_in[0];
  const float* gsc  = (const float*)d_in[1];
  const float* gbs  = (const float*)d_in[2];
  const float* wqkv = (const float*)d_in[3];
  const float* bqkv = (const float*)d_in[4];
  const float* wout = (const float*)d_in[5];
  const float* bout = (const float*)d_in[6];
  float* out = (float*)d_out;

  char* ws = (char*)d_ws;
  unsigned short* xn    = (unsigned short*)(ws);                 // 8 MB (8192x512)
  unsigned short* wqkvt = (unsigned short*)(ws + 8388608);       // 1.5 MB (1536x512)
  unsigned short* woutt = (unsigned short*)(ws + 9961472);       // 0.5 MB (512x512)
  unsigned short* qb    = (unsigned short*)(ws + 10485760);      // 8 MB (64,1024,64)
  unsigned short* kb    = (unsigned short*)(ws + 18874368);      // 8 MB (64,1024,64)
  unsigned short* vtb   = (unsigned short*)(ws + 27262976);      // 8 MB (64,64,1024)
  unsigned short* ao    = (unsigned short*)(ws + 35651584);      // 8 MB (8192x512)

  prep_kernel<<<512, 1024, 0, stream>>>(wqkv, wout, x, gsc, gbs, wqkvt, woutt, xn);
  gemm_bt_kernel<0, 128><<<dim3(64, 12), 256, 0, stream>>>(
      xn, wqkvt, 512, 1536, bqkv, nullptr, nullptr, qb, kb, vtb);
  attn_kernel<<<dim3(64, 8), 256, 0, stream>>>(qb, kb, vtb, ao);
  gemm_bt_kernel<1, 64><<<dim3(128, 4), 256, 0, stream>>>(
      ao, woutt, 512, 512, bout, x, out, nullptr, nullptr, nullptr);
}

// Round 7
// 145.525 us; speedup vs baseline: 1.2013x; 1.2013x over previous
//
#include <hip/hip_runtime.h>
#include <hip/hip_bf16.h>

// B=8, H=W=32 (seq=1024), C=512, heads=8, head_dim=64, groups=32
#define SEQ   1024
#define CH    512
#define NHEAD 8
#define HDIM  64
#define BATCH 8

using short8  = __attribute__((ext_vector_type(8))) short;
using floatx4 = __attribute__((ext_vector_type(4))) float;
using uint4v  = __attribute__((ext_vector_type(4))) unsigned int;

#if __has_builtin(__builtin_amdgcn_exp2f)
#define EXP2F __builtin_amdgcn_exp2f
#else
#define EXP2F exp2f
#endif

__device__ inline unsigned short f2bf(float f) {
  __hip_bfloat16 h = __float2bfloat16(f);
  return __builtin_bit_cast(unsigned short, h);
}

// packed f32x2 -> bf16x2 (RNE), single VALU inst; low half = first arg
__device__ inline unsigned int cvt_pk_bf16(float lo, float hi) {
  unsigned int r;
  asm("v_cvt_pk_bf16_f32 %0, %1, %2" : "=v"(r) : "v"(lo), "v"(hi));
  return r;
}

// async 16B global->LDS DMA (lane-linear LDS dest required)
__device__ inline void load_lds16(const void* g, void* l) {
  __builtin_amdgcn_global_load_lds(
      (const __attribute__((address_space(1))) unsigned int*)g,
      (__attribute__((address_space(3))) unsigned int*)l, 16, 0, 0);
}

// ---------------------------------------------------------------------------
// K1 (fused): blocks 0..255 = GroupNorm for one (b,g).  Each thread's 16
// values (4x float4) are held in REGISTERS across the stats reduction --
// no 64KB LDS round-trip.  LDS is only the 17KB transpose tile + scratch.
// Blocks 256..447: wqkv transpose (64x64 tiles); 448..511: wout transpose.
// ---------------------------------------------------------------------------
__global__ __launch_bounds__(1024) void prep_kernel(
    const float* __restrict__ wqkv, const float* __restrict__ wout,
    const float* __restrict__ x, const float* __restrict__ gsc,
    const float* __restrict__ gbs,
    unsigned short* __restrict__ wqkvt, unsigned short* __restrict__ woutt,
    unsigned short* __restrict__ xn) {
  __shared__ float SH[64 * 65 + 32];   // transpose tile + reduce scratch
  const int blk = blockIdx.x, tid = threadIdx.x;

  if (blk >= 256) {
    // ---- weight transpose, 64x64 tile, bf16 out ----
    const float* src; unsigned short* dst; int C, bx, by;
    if (blk < 448) { int t = blk - 256; src = wqkv; dst = wqkvt; C = 1536; bx = t % 24; by = t / 24; }
    else           { int t = blk - 448; src = wout; dst = woutt; C = 512;  bx = t & 7;  by = t >> 3; }
    float (*T)[65] = (float(*)[65])SH;
    int tx = tid & 63, ty = tid >> 6;            // ty 0..15
    for (int j = 0; j < 4; ++j)
      T[ty + j * 16][tx] = src[(size_t)(by * 64 + ty + j * 16) * C + bx * 64 + tx];
    __syncthreads();
    for (int j = 0; j < 4; ++j)
      dst[(size_t)(bx * 64 + ty + j * 16) * 512 + by * 64 + tx] = f2bf(T[tx][ty + j * 16]);
    return;
  }

  // ---- GroupNorm, one (b,g) per block; tile kept in registers ----
  const int b = blk >> 5, g = blk & 31;
  const size_t base = (size_t)b * SEQ * CH + g * 16;

  float4 v[4];
  float s = 0.f, sq = 0.f;
  for (int i = 0; i < 4; ++i) {
    int c = (i << 10) + tid;                     // 4096 float4 chunks
    int r = c >> 2, c4 = (c & 3) << 2;
    v[i] = *(const float4*)(x + base + (size_t)r * CH + c4);
    s  += v[i].x + v[i].y + v[i].z + v[i].w;
    sq += v[i].x * v[i].x + v[i].y * v[i].y + v[i].z * v[i].z + v[i].w * v[i].w;
  }
  for (int off = 1; off < 64; off <<= 1) {
    s  += __shfl_xor(s, off);
    sq += __shfl_xor(sq, off);
  }
  const int wid = tid >> 6, lane = tid & 63;
  float* scr = SH + 64 * 65;
  if (lane == 0) { scr[wid] = s; scr[16 + wid] = sq; }
  __syncthreads();
  float ts = 0.f, tq = 0.f;
  for (int i = 0; i < 16; ++i) { ts += scr[i]; tq += scr[16 + i]; }
  const float inv_n = 1.0f / 16384.0f;
  float mean = ts * inv_n;
  float var  = tq * inv_n - mean * mean;
  float rstd = rsqrtf(var + 1e-6f);

  int c4 = (tid & 3) << 2;
  float4 sc = *(const float4*)(gsc + g * 16 + c4);
  float4 bs = *(const float4*)(gbs + g * 16 + c4);
  for (int i = 0; i < 4; ++i) {
    int c = (i << 10) + tid;
    int r = c >> 2;
    ushort4 o;
    o.x = f2bf((v[i].x - mean) * rstd * sc.x + bs.x);
    o.y = f2bf((v[i].y - mean) * rstd * sc.y + bs.y);
    o.z = f2bf((v[i].z - mean) * rstd * sc.z + bs.z);
    o.w = f2bf((v[i].w - mean) * rstd * sc.w + bs.w);
    *(ushort4*)(xn + base + (size_t)r * CH + c4) = o;
  }
}

// ---------------------------------------------------------------------------
// K2/K4: GEMM C = A(MxK) * Bt(NxK)^T, bf16 in, fp32 acc, MTILE x 128 tile.
// Grid is (m-tile, n-tile) so blocks sharing an A-tile get the same
// linear%8 -> same XCD (L2 locality).  BK=64, global_load_lds staging,
// XOR-swizzled LDS.  Epilogues via LDS -> 16B global stores.
// EPI 0 (MTILE=128, QKV): +bias; q scaled (1/64)*log2e; q/k -> (h,s,d);
//     v -> transposed vt (h,d,s) with s permuted within 32-blocks so attn
//     PV P-frags form 16x16x32 A-operands with zero cross-lane ops.
// EPI 1 (MTILE=64, out):  +bias +residual, fp32 out.
// ---------------------------------------------------------------------------
template <int EPI, int MTILE>
__global__ __launch_bounds__(256) void gemm_bt_kernel(
    const unsigned short* __restrict__ A, const unsigned short* __restrict__ Bt,
    int K, int N,
    const float* __restrict__ bias, const float* __restrict__ resid,
    float* __restrict__ outf,
    unsigned short* __restrict__ qb, unsigned short* __restrict__ kb,
    unsigned short* __restrict__ vtb) {
  constexpr int SMSZ = (MTILE == 128) ? 17408 : 16896;
  constexpr int NI   = (MTILE == 128) ? 4 : 2;
  __shared__ alignas(16) unsigned short SM[SMSZ];
  unsigned short* LA = SM;                 // MTILE x 64, swizzled
  unsigned short* LB = SM + MTILE * 64;    // 128 x 64, swizzled

  const int tid = threadIdx.x;
  const int wid = tid >> 6, lane = tid & 63;
  const int quad = lane >> 4, m16 = lane & 15;
  const int sw = m16 & 7;
  const int wm = (MTILE == 128) ? (wid & 1) * 64 : 0;
  const int wn = (MTILE == 128) ? (wid >> 1) * 64 : wid * 32;
  const int m0 = blockIdx.x * MTILE, n0 = blockIdx.y * 128;

  floatx4 acc[4][NI];
  for (int i = 0; i < 4; ++i)
    for (int j = 0; j < NI; ++j) acc[i][j] = 0.f;

  for (int k0 = 0; k0 < K; k0 += 64) {
    for (int i = 0; i < MTILE / 32; ++i) {
      int c = i * 256 + tid;
      int r = c >> 3, kc = c & 7;
      load_lds16(A + (size_t)(m0 + r) * K + k0 + ((kc ^ (r & 7)) << 3), &LA[c << 3]);
    }
    for (int i = 0; i < 4; ++i) {
      int c = i * 256 + tid;
      int r = c >> 3, kc = c & 7;
      load_lds16(Bt + (size_t)(n0 + r) * K + k0 + ((kc ^ (r & 7)) << 3), &LB[c << 3]);
    }
    __syncthreads();
    for (int kq = 0; kq < 2; ++kq) {
      int csw = (((kq << 2) + quad) ^ sw) << 3;
      short8 af[4], bf[NI];
      for (int mi = 0; mi < 4; ++mi)
        af[mi] = *(const short8*)&LA[(wm + mi * 16 + m16) * 64 + csw];
      for (int ni = 0; ni < NI; ++ni)
        bf[ni] = *(const short8*)&LB[(wn + ni * 16 + m16) * 64 + csw];
      for (int mi = 0; mi < 4; ++mi)
        for (int ni = 0; ni < NI; ++ni)
          acc[mi][ni] = __builtin_amdgcn_mfma_f32_16x16x32_bf16(af[mi], bf[ni], acc[mi][ni], 0, 0, 0);
    }
    __syncthreads();
  }

  // C/D layout: row = quad*4+reg, col = lane&15
  const int b = m0 >> 10;
  if (EPI == 0) {
    const int part = n0 >> 9;                // 0=q 1=k 2=v (block-uniform)
    if (part < 2) {
      const float qscale = (part == 0) ? 0.0225421381f : 1.0f;  // (1/64)*log2e
      unsigned short* dst = (part == 0) ? qb : kb;
      for (int mi = 0; mi < 4; ++mi)
        for (int ni = 0; ni < 4; ++ni) {
          int ln = wn + ni * 16 + m16;
          float bb = bias[n0 + ln];
          for (int reg = 0; reg < 4; ++reg)
            SM[(wm + mi * 16 + quad * 4 + reg) * 136 + ln] =
                f2bf((acc[mi][ni][reg] + bb) * qscale);
        }
      __syncthreads();
      const int colb = n0 & 511;
      for (int j = 0; j < 8; ++j) {
        int c = j * 256 + tid;               // 2048 16B chunks
        int m = c >> 4, n8 = (c & 15) * 8;
        int h = (colb + n8) >> 6, d = n8 & 63;
        int sp = (m0 & 1023) + m;
        int4 v = *(const int4*)&SM[m * 136 + n8];
        *(int4*)(dst + (((size_t)(b * NHEAD + h)) * SEQ + sp) * HDIM + d) = v;
      }
    } else {
      // v: transpose [n][m], m permuted within 32-blocks (slot = 32*(mblk>>1)
      // + 8*quad + 4*(mblk&1) + reg) for attn's K=32 PV A-operands
      for (int mi = 0; mi < 4; ++mi)
        for (int ni = 0; ni < 4; ++ni) {
          int ln = wn + ni * 16 + m16;
          float bb = bias[n0 + ln];
          int mblk = (wm >> 4) + mi;
          int sbase = 32 * (mblk >> 1) + 8 * quad + 4 * (mblk & 1);
          for (int reg = 0; reg < 4; ++reg)
            SM[ln * 136 + sbase + reg] = f2bf(acc[mi][ni][reg] + bb);
        }
      __syncthreads();
      int hbase = (n0 - 1024) >> 6;
      for (int j = 0; j < 8; ++j) {
        int c = j * 256 + tid;
        int ld = c >> 4, sp8 = (c & 15) * 8;
        int h = hbase + (ld >> 6), d = ld & 63;
        int4 v = *(const int4*)&SM[ld * 136 + sp8];
        *(int4*)(vtb + ((size_t)(b * NHEAD + h) * HDIM + d) * SEQ + (m0 & 1023) + sp8) = v;
      }
    }
  } else {
    float* SMf = (float*)SM;                 // 64 x 132 fp32
    for (int mi = 0; mi < 4; ++mi)
      for (int ni = 0; ni < NI; ++ni) {
        int ln = wn + ni * 16 + m16;
        float bb = bias[n0 + ln];
        for (int reg = 0; reg < 4; ++reg)
          SMf[(mi * 16 + quad * 4 + reg) * 132 + ln] = acc[mi][ni][reg] + bb;
      }
    __syncthreads();
    for (int j = 0; j < 8; ++j) {
      int c = j * 256 + tid;                 // 2048 float4 chunks
      int m = c >> 5, n4 = (c & 31) * 4;
      size_t idx = (size_t)(m0 + m) * N + n0 + n4;
      float4 v = *(const float4*)&SMf[m * 132 + n4];
      float4 rr = *(const float4*)&resid[idx];
      v.x += rr.x; v.y += rr.y; v.z += rr.z; v.w += rr.w;
      *(float4*)&outf[idx] = v;
    }
  }
}

// ---------------------------------------------------------------------------
// K3: flash attention.  r6 post-mortem: reg-staging (T14) was demoted to
// scratch by the compiler regardless of launch bounds (VGPR=60, ~83MB spill
// writes) -- T14 dropped.  Staging reverts to global_load_lds (r4 known-good)
// PLUS the T3 2-phase double-buffer: next tile's DMA is issued into buf^1
// BEFORE computing buf, one barrier per kt (drains vmcnt; loads had the whole
// compute phase to land).  64KB LDS is free: grid (512 blocks) caps us at
// 2 blocks/CU anyway.  No staging registers -> no scratch risk.
// Keeps: 32 q-rows/wave, raw v_exp_f32, packed cvt_pk_bf16, ones-column
// MFMA denominator, setprio, LDS-coalesced epilogue.
// ---------------------------------------------------------------------------
__global__ __launch_bounds__(256, 4) void attn_kernel(
    const unsigned short* __restrict__ qb, const unsigned short* __restrict__ kb,
    const unsigned short* __restrict__ vtb, unsigned short* __restrict__ ao) {
  const int head = blockIdx.x, qt = blockIdx.y;
  const int b = head >> 3, h = head & 7;
  const int tid = threadIdx.x;
  const int wid = tid >> 6, lane = tid & 63;
  const int quad = lane >> 4, m16 = lane & 15;
  const int sw = m16 & 7;

  __shared__ alignas(16) unsigned short SMEM[32768];   // 64 KB (2 x 32KB buf)
  // buffer n: sK at SMEM + n*16384, sV at SMEM + n*16384 + 8192

  const unsigned short* kbase = kb  + (size_t)head * SEQ * HDIM;
  const unsigned short* vbase = vtb + (size_t)head * HDIM * SEQ;

  // Q fragments for two 16-row q-blocks (pre-scaled by (1/64)*log2e upstream)
  short8 aq[2][2];
  for (int qblk = 0; qblk < 2; ++qblk) {
    const size_t qrow = (size_t)head * SEQ + qt * 128 + wid * 32 + qblk * 16 + m16;
    aq[qblk][0] = *(const short8*)(qb + qrow * HDIM + quad * 8);
    aq[qblk][1] = *(const short8*)(qb + qrow * HDIM + 32 + quad * 8);
  }

  const unsigned int onep = 0x3F803F80u;               // bf16(1.0) x2
  const short8 vones = __builtin_bit_cast(short8, (uint4v){onep, onep, onep, onep});

  floatx4 la[2];                                       // denominators, D-layout
  floatx4 o[2][4];
  for (int qblk = 0; qblk < 2; ++qblk) {
    la[qblk] = 0.f;
    for (int df = 0; df < 4; ++df) o[qblk][df] = 0.f;
  }

  // prologue: stage tile 0 into buffer 0 (4 K-chunks + 4 V-chunks per thread)
  for (int i = 0; i < 4; ++i) {
    int c = i * 256 + tid;
    int r = c >> 3, kc = c & 7;
    load_lds16(kbase + r * HDIM + ((kc ^ (r & 7)) << 3), &SMEM[c << 3]);
  }
  for (int i = 0; i < 4; ++i) {
    int c = i * 256 + tid;
    int d = c >> 4, kc = c & 15;
    load_lds16(vbase + d * SEQ + ((kc ^ (d & 7)) << 3), &SMEM[8192 + (c << 3)]);
  }
  __syncthreads();

  int buf = 0;
  for (int kt = 0; kt < 8; ++kt) {
    unsigned short* sK = SMEM + buf * 16384;
    unsigned short* sV = SMEM + buf * 16384 + 8192;

    // T3: issue next tile's DMA into the other buffer before compute;
    // the end-of-iteration barrier's vmcnt(0) drain lands after ~1500cyc
    // of MFMA/softmax -- loads are long done.
    if (kt < 7) {
      unsigned short* nK = SMEM + (buf ^ 1) * 16384;
      unsigned short* nV = nK + 8192;
      const int kn = kt + 1;
      for (int i = 0; i < 4; ++i) {
        int c = i * 256 + tid;
        int r = c >> 3, kc = c & 7;
        load_lds16(kbase + (kn * 128 + r) * HDIM + ((kc ^ (r & 7)) << 3), &nK[c << 3]);
      }
      for (int i = 0; i < 4; ++i) {
        int c = i * 256 + tid;
        int d = c >> 4, kc = c & 15;
        load_lds16(vbase + d * SEQ + kn * 128 + ((kc ^ (d & 7)) << 3), &nV[c << 3]);
      }
    }

    // per-u: QK^T for the 2 sub-frags -> exp2 -> pack -> PV immediately.
    // sf=2u+t -> A-operand k=quad*8+4t+r.  pw live range = one u (8 VGPR).
    for (int u = 0; u < 4; ++u) {
      unsigned int pw[2][4];
      for (int t = 0; t < 2; ++t) {
        const int sf = u * 2 + t;
        const int rb = (sf * 16 + m16) * 64;
        short8 k0 = *(const short8*)&sK[rb + ((quad ^ sw) << 3)];
        short8 k1 = *(const short8*)&sK[rb + (((4 + quad) ^ sw) << 3)];
        floatx4 s0 = 0.f, s1 = 0.f;
        __builtin_amdgcn_s_setprio(1);
        s0 = __builtin_amdgcn_mfma_f32_16x16x32_bf16(k0, aq[0][0], s0, 0, 0, 0);
        s0 = __builtin_amdgcn_mfma_f32_16x16x32_bf16(k1, aq[0][1], s0, 0, 0, 0);
        s1 = __builtin_amdgcn_mfma_f32_16x16x32_bf16(k0, aq[1][0], s1, 0, 0, 0);
        s1 = __builtin_amdgcn_mfma_f32_16x16x32_bf16(k1, aq[1][1], s1, 0, 0, 0);
        __builtin_amdgcn_s_setprio(0);
        pw[0][t * 2 + 0] = cvt_pk_bf16(EXP2F(s0[0]), EXP2F(s0[1]));
        pw[0][t * 2 + 1] = cvt_pk_bf16(EXP2F(s0[2]), EXP2F(s0[3]));
        pw[1][t * 2 + 0] = cvt_pk_bf16(EXP2F(s1[0]), EXP2F(s1[1]));
        pw[1][t * 2 + 1] = cvt_pk_bf16(EXP2F(s1[2]), EXP2F(s1[3]));
      }
      const short8 pf0 = __builtin_bit_cast(
          short8, (uint4v){pw[0][0], pw[0][1], pw[0][2], pw[0][3]});
      const short8 pf1 = __builtin_bit_cast(
          short8, (uint4v){pw[1][0], pw[1][1], pw[1][2], pw[1][3]});
      const int chunk = ((u * 4 + quad) ^ sw) << 3;
      __builtin_amdgcn_s_setprio(1);
      for (int df = 0; df < 4; ++df) {
        short8 bv = *(const short8*)&sV[(df * 16 + m16) * 128 + chunk];
        o[0][df] = __builtin_amdgcn_mfma_f32_16x16x32_bf16(pf0, bv, o[0][df], 0, 0, 0);
        o[1][df] = __builtin_amdgcn_mfma_f32_16x16x32_bf16(pf1, bv, o[1][df], 0, 0, 0);
      }
      la[0] = __builtin_amdgcn_mfma_f32_16x16x32_bf16(pf0, vones, la[0], 0, 0, 0);
      la[1] = __builtin_amdgcn_mfma_f32_16x16x32_bf16(pf1, vones, la[1], 0, 0, 0);
      __builtin_amdgcn_s_setprio(0);
    }
    __syncthreads();   // drains vmcnt(0): next buffer ready; this buffer free
    buf ^= 1;
  }

  // normalize into f32 scratch [128][64] (32KB, first half), coalesced write
  float* Sc = (float*)SMEM;
  for (int qblk = 0; qblk < 2; ++qblk) {
    floatx4 lr;
    for (int r = 0; r < 4; ++r) lr[r] = 1.0f / la[qblk][r];
    const int row0 = wid * 32 + qblk * 16 + quad * 4;
    for (int df = 0; df < 4; ++df) {
      const int col = df * 16 + m16;
      Sc[(row0 + 0) * 64 + col] = o[qblk][df][0] * lr[0];
      Sc[(row0 + 1) * 64 + col] = o[qblk][df][1] * lr[1];
      Sc[(row0 + 2) * 64 + col] = o[qblk][df][2] * lr[2];
      Sc[(row0 + 3) * 64 + col] = o[qblk][df][3] * lr[3];
    }
  }
  __syncthreads();
  for (int j = 0; j < 4; ++j) {
    int c = j * 256 + tid;             // 1024 8-col chunks
    int m = c >> 3, n8 = (c & 7) * 8;
    floatx4 v0 = *(const floatx4*)&Sc[m * 64 + n8];
    floatx4 v1 = *(const floatx4*)&Sc[m * 64 + n8 + 4];
    int4 w;
    w.x = (int)cvt_pk_bf16(v0[0], v0[1]);
    w.y = (int)cvt_pk_bf16(v0[2], v0[3]);
    w.z = (int)cvt_pk_bf16(v1[0], v1[1]);
    w.w = (int)cvt_pk_bf16(v1[2], v1[3]);
    *(int4*)(ao + (size_t)(b * SEQ + qt * 128 + m) * CH + h * HDIM + n8) = w;
  }
}

// ---------------------------------------------------------------------------
extern "C" void kernel_launch(void* const* d_in, const int* in_sizes, int n_in,
                              void* d_out, int out_size, void* d_ws, size_t ws_size,
                              hipStream_t stream) {
  const float* x    = (const float*)d_in[0];
  const float* gsc  = (const float*)d_in[1];
  const float* gbs  = (const float*)d_in[2];
  const float* wqkv = (const float*)d_in[3];
  const float* bqkv = (const float*)d_in[4];
  const float* wout = (const float*)d_in[5];
  const float* bout = (const float*)d_in[6];
  float* out = (float*)d_out;

  char* ws = (char*)d_ws;
  unsigned short* xn    = (unsigned short*)(ws);                 // 8 MB (8192x512)
  unsigned short* wqkvt = (unsigned short*)(ws + 8388608);       // 1.5 MB (1536x512)
  unsigned short* woutt = (unsigned short*)(ws + 9961472);       // 0.5 MB (512x512)
  unsigned short* qb    = (unsigned short*)(ws + 10485760);      // 8 MB (64,1024,64)
  unsigned short* kb    = (unsigned short*)(ws + 18874368);      // 8 MB (64,1024,64)
  unsigned short* vtb   = (unsigned short*)(ws + 27262976);      // 8 MB (64,64,1024)
  unsigned short* ao    = (unsigned short*)(ws + 35651584);      // 8 MB (8192x512)

  prep_kernel<<<512, 1024, 0, stream>>>(wqkv, wout, x, gsc, gbs, wqkvt, woutt, xn);
  gemm_bt_kernel<0, 128><<<dim3(64, 12), 256, 0, stream>>>(
      xn, wqkvt, 512, 1536, bqkv, nullptr, nullptr, qb, kb, vtb);
  attn_kernel<<<dim3(64, 8), 256, 0, stream>>>(qb, kb, vtb, ao);
  gemm_bt_kernel<1, 64><<<dim3(128, 4), 256, 0, stream>>>(
      ao, woutt, 512, 512, bout, x, out, nullptr, nullptr, nullptr);
}

// Round 8
// 135.853 us; speedup vs baseline: 1.2868x; 1.0712x over previous
//
#include <hip/hip_runtime.h>
#include <hip/hip_bf16.h>

// B=8, H=W=32 (seq=1024), C=512, heads=8, head_dim=64, groups=32
#define SEQ   1024
#define CH    512
#define NHEAD 8
#define HDIM  64
#define BATCH 8

using short8  = __attribute__((ext_vector_type(8))) short;
using floatx4 = __attribute__((ext_vector_type(4))) float;
using uint4v  = __attribute__((ext_vector_type(4))) unsigned int;

#if __has_builtin(__builtin_amdgcn_exp2f)
#define EXP2F __builtin_amdgcn_exp2f
#else
#define EXP2F exp2f
#endif

__device__ inline unsigned short f2bf(float f) {
  __hip_bfloat16 h = __float2bfloat16(f);
  return __builtin_bit_cast(unsigned short, h);
}

// packed f32x2 -> bf16x2 (RNE), single VALU inst; low half = first arg
__device__ inline unsigned int cvt_pk_bf16(float lo, float hi) {
  unsigned int r;
  asm("v_cvt_pk_bf16_f32 %0, %1, %2" : "=v"(r) : "v"(lo), "v"(hi));
  return r;
}

// async 16B global->LDS DMA (lane-linear LDS dest required)
__device__ inline void load_lds16(const void* g, void* l) {
  __builtin_amdgcn_global_load_lds(
      (const __attribute__((address_space(1))) unsigned int*)g,
      (__attribute__((address_space(3))) unsigned int*)l, 16, 0, 0);
}

// ---------------------------------------------------------------------------
// K1 (fused, r4-verbatim): blocks 0..255 = GroupNorm for one (b,g) staged in
// LDS; blocks 256..447 wqkv transpose; 448..511 wout transpose.
// ---------------------------------------------------------------------------
__global__ __launch_bounds__(1024) void prep_kernel(
    const float* __restrict__ wqkv, const float* __restrict__ wout,
    const float* __restrict__ x, const float* __restrict__ gsc,
    const float* __restrict__ gbs,
    unsigned short* __restrict__ wqkvt, unsigned short* __restrict__ woutt,
    unsigned short* __restrict__ xn) {
  __shared__ float SH[16416];   // 64 KB tile + 32 floats reduce scratch
  const int blk = blockIdx.x, tid = threadIdx.x;

  if (blk >= 256) {
    const float* src; unsigned short* dst; int C, bx, by;
    if (blk < 448) { int t = blk - 256; src = wqkv; dst = wqkvt; C = 1536; bx = t % 24; by = t / 24; }
    else           { int t = blk - 448; src = wout; dst = woutt; C = 512;  bx = t & 7;  by = t >> 3; }
    float (*T)[65] = (float(*)[65])SH;
    int tx = tid & 63, ty = tid >> 6;            // ty 0..15
    for (int j = 0; j < 4; ++j)
      T[ty + j * 16][tx] = src[(size_t)(by * 64 + ty + j * 16) * C + bx * 64 + tx];
    __syncthreads();
    for (int j = 0; j < 4; ++j)
      dst[(size_t)(bx * 64 + ty + j * 16) * 512 + by * 64 + tx] = f2bf(T[tx][ty + j * 16]);
    return;
  }

  const int b = blk >> 5, g = blk & 31;
  const size_t base = (size_t)b * SEQ * CH + g * 16;

  float s = 0.f, sq = 0.f;
  for (int i = 0; i < 4; ++i) {
    int c = (i << 10) + tid;                     // 4096 float4 chunks
    int r = c >> 2, c4 = (c & 3) << 2;
    float4 v = *(const float4*)(x + base + (size_t)r * CH + c4);
    *(float4*)&SH[c << 2] = v;
    s  += v.x + v.y + v.z + v.w;
    sq += v.x * v.x + v.y * v.y + v.z * v.z + v.w * v.w;
  }
  for (int off = 1; off < 64; off <<= 1) {
    s  += __shfl_xor(s, off);
    sq += __shfl_xor(sq, off);
  }
  const int wid = tid >> 6, lane = tid & 63;
  if (lane == 0) { SH[16384 + wid] = s; SH[16400 + wid] = sq; }
  __syncthreads();
  float ts = 0.f, tq = 0.f;
  for (int i = 0; i < 16; ++i) { ts += SH[16384 + i]; tq += SH[16400 + i]; }
  const float inv_n = 1.0f / 16384.0f;
  float mean = ts * inv_n;
  float var  = tq * inv_n - mean * mean;
  float rstd = rsqrtf(var + 1e-6f);

  int c4 = (tid & 3) << 2;
  float4 sc = *(const float4*)(gsc + g * 16 + c4);
  float4 bs = *(const float4*)(gbs + g * 16 + c4);
  for (int i = 0; i < 4; ++i) {
    int c = (i << 10) + tid;
    int r = c >> 2;
    float4 v = *(const float4*)&SH[c << 2];
    ushort4 o;
    o.x = f2bf((v.x - mean) * rstd * sc.x + bs.x);
    o.y = f2bf((v.y - mean) * rstd * sc.y + bs.y);
    o.z = f2bf((v.z - mean) * rstd * sc.z + bs.z);
    o.w = f2bf((v.w - mean) * rstd * sc.w + bs.w);
    *(ushort4*)(xn + base + (size_t)r * CH + c4) = o;
  }
}

// ---------------------------------------------------------------------------
// K2 (NEW this round): QKV GEMM, 128(M) x 256(N) tile, 512 threads, 8 waves
// (2M x 4N, 64x64 per wave).  vs the old 128x128/256thr: staging bytes per
// output -25%, barriers per output halved, grid 768->384 blocks (all
// co-resident: 48KB LDS -> 2 blocks/CU, 16 waves/CU).  K-loop body identical
// in pattern (BK=64, global_load_lds, XOR swizzle).  Each 256-col n-tile lies
// in exactly one of q/k/v (1536 = 2+2+2 tiles).  Epilogue does two 128-col
// halves through the same [128][136] LDS staging as before.
// ---------------------------------------------------------------------------
__global__ __launch_bounds__(512) void gemm_qkv_kernel(
    const unsigned short* __restrict__ A, const unsigned short* __restrict__ Bt,
    const float* __restrict__ bias,
    unsigned short* __restrict__ qb, unsigned short* __restrict__ kb,
    unsigned short* __restrict__ vtb) {
  constexpr int K = 512;
  __shared__ alignas(16) unsigned short SM[24576];   // 48 KB
  unsigned short* LA = SM;          // 128 x 64, swizzled (16 KB)
  unsigned short* LB = SM + 8192;   // 256 x 64, swizzled (32 KB)

  const int tid = threadIdx.x;
  const int wid = tid >> 6, lane = tid & 63;
  const int quad = lane >> 4, m16 = lane & 15;
  const int sw = m16 & 7;
  const int wm = (wid & 1) * 64;          // 2 M-warps
  const int wn = (wid >> 1) * 64;         // 4 N-warps (0,64,128,192)
  const int m0 = blockIdx.x * 128, n0 = blockIdx.y * 256;

  floatx4 acc[4][4];
  for (int i = 0; i < 4; ++i)
    for (int j = 0; j < 4; ++j) acc[i][j] = 0.f;

  for (int k0 = 0; k0 < K; k0 += 64) {
    for (int i = 0; i < 2; ++i) {          // A: 1024 16B chunks
      int c = i * 512 + tid;
      int r = c >> 3, kc = c & 7;
      load_lds16(A + (size_t)(m0 + r) * K + k0 + ((kc ^ (r & 7)) << 3), &LA[c << 3]);
    }
    for (int i = 0; i < 4; ++i) {          // B: 2048 16B chunks
      int c = i * 512 + tid;
      int r = c >> 3, kc = c & 7;
      load_lds16(Bt + (size_t)(n0 + r) * K + k0 + ((kc ^ (r & 7)) << 3), &LB[c << 3]);
    }
    __syncthreads();
    for (int kq = 0; kq < 2; ++kq) {
      int csw = (((kq << 2) + quad) ^ sw) << 3;
      short8 af[4], bf[4];
      for (int mi = 0; mi < 4; ++mi)
        af[mi] = *(const short8*)&LA[(wm + mi * 16 + m16) * 64 + csw];
      for (int ni = 0; ni < 4; ++ni)
        bf[ni] = *(const short8*)&LB[(wn + ni * 16 + m16) * 64 + csw];
      for (int mi = 0; mi < 4; ++mi)
        for (int ni = 0; ni < 4; ++ni)
          acc[mi][ni] = __builtin_amdgcn_mfma_f32_16x16x32_bf16(af[mi], bf[ni], acc[mi][ni], 0, 0, 0);
    }
    __syncthreads();
  }

  // C/D layout: row = quad*4+reg, col = lane&15.  Two 128-col halves.
  const int b = m0 >> 10;
  const int part = n0 >> 9;                // 0=q 1=k 2=v (block-uniform)
  if (part < 2) {
    const float qscale = (part == 0) ? 0.0225421381f : 1.0f;  // (1/64)*log2e
    unsigned short* dst = (part == 0) ? qb : kb;
    for (int half = 0; half < 2; ++half) {
      if ((wn >> 7) == half) {
        for (int mi = 0; mi < 4; ++mi)
          for (int ni = 0; ni < 4; ++ni) {
            int ln = (wn & 127) + ni * 16 + m16;
            float bb = bias[n0 + half * 128 + ln];
            for (int reg = 0; reg < 4; ++reg)
              SM[(wm + mi * 16 + quad * 4 + reg) * 136 + ln] =
                  f2bf((acc[mi][ni][reg] + bb) * qscale);
          }
      }
      __syncthreads();
      const int colb = (n0 & 511) + half * 128;
      for (int j = 0; j < 4; ++j) {
        int c = j * 512 + tid;               // 2048 16B chunks (128x128)
        int m = c >> 4, n8 = (c & 15) * 8;
        int h = (colb + n8) >> 6, d = (colb + n8) & 63;
        int sp = (m0 & 1023) + m;
        int4 v = *(const int4*)&SM[m * 136 + n8];
        *(int4*)(dst + (((size_t)(b * NHEAD + h)) * SEQ + sp) * HDIM + d) = v;
      }
      __syncthreads();
    }
  } else {
    // v: transpose [n][m], m permuted within 32-blocks (slot = 32*(mblk>>1)
    // + 8*quad + 4*(mblk&1) + reg) for attn's K=32 PV A-operands
    for (int half = 0; half < 2; ++half) {
      if ((wn >> 7) == half) {
        for (int mi = 0; mi < 4; ++mi)
          for (int ni = 0; ni < 4; ++ni) {
            int ln = (wn & 127) + ni * 16 + m16;
            float bb = bias[n0 + half * 128 + ln];
            int mblk = (wm >> 4) + mi;       // 0..7 over 128 rows
            int sbase = 32 * (mblk >> 1) + 8 * quad + 4 * (mblk & 1);
            for (int reg = 0; reg < 4; ++reg)
              SM[ln * 136 + sbase + reg] = f2bf(acc[mi][ni][reg] + bb);
          }
      }
      __syncthreads();
      const int vcolb = (n0 - 1024) + half * 128;
      for (int j = 0; j < 4; ++j) {
        int c = j * 512 + tid;               // 2048 16B chunks (128x128)
        int ld = c >> 4, sp8 = (c & 15) * 8;
        int h = (vcolb + ld) >> 6, d = (vcolb + ld) & 63;
        int4 v = *(const int4*)&SM[ld * 136 + sp8];
        *(int4*)(vtb + ((size_t)(b * NHEAD + h) * HDIM + d) * SEQ + (m0 & 1023) + sp8) = v;
      }
      __syncthreads();
    }
  }
}

// ---------------------------------------------------------------------------
// K4: out GEMM (was template EPI=1): 64x128 tile, 256 thr, +bias +residual,
// fp32 out.  Unchanged structure.
// ---------------------------------------------------------------------------
__global__ __launch_bounds__(256) void gemm_out_kernel(
    const unsigned short* __restrict__ A, const unsigned short* __restrict__ Bt,
    const float* __restrict__ bias, const float* __restrict__ resid,
    float* __restrict__ outf) {
  constexpr int K = 512, N = 512;
  __shared__ alignas(16) unsigned short SM[16896];
  unsigned short* LA = SM;                 // 64 x 64, swizzled
  unsigned short* LB = SM + 64 * 64;       // 128 x 64, swizzled

  const int tid = threadIdx.x;
  const int wid = tid >> 6, lane = tid & 63;
  const int quad = lane >> 4, m16 = lane & 15;
  const int sw = m16 & 7;
  const int wn = wid * 32;
  const int m0 = blockIdx.x * 64, n0 = blockIdx.y * 128;

  floatx4 acc[4][2];
  for (int i = 0; i < 4; ++i)
    for (int j = 0; j < 2; ++j) acc[i][j] = 0.f;

  for (int k0 = 0; k0 < K; k0 += 64) {
    for (int i = 0; i < 2; ++i) {
      int c = i * 256 + tid;
      int r = c >> 3, kc = c & 7;
      load_lds16(A + (size_t)(m0 + r) * K + k0 + ((kc ^ (r & 7)) << 3), &LA[c << 3]);
    }
    for (int i = 0; i < 4; ++i) {
      int c = i * 256 + tid;
      int r = c >> 3, kc = c & 7;
      load_lds16(Bt + (size_t)(n0 + r) * K + k0 + ((kc ^ (r & 7)) << 3), &LB[c << 3]);
    }
    __syncthreads();
    for (int kq = 0; kq < 2; ++kq) {
      int csw = (((kq << 2) + quad) ^ sw) << 3;
      short8 af[4], bf[2];
      for (int mi = 0; mi < 4; ++mi)
        af[mi] = *(const short8*)&LA[(mi * 16 + m16) * 64 + csw];
      for (int ni = 0; ni < 2; ++ni)
        bf[ni] = *(const short8*)&LB[(wn + ni * 16 + m16) * 64 + csw];
      for (int mi = 0; mi < 4; ++mi)
        for (int ni = 0; ni < 2; ++ni)
          acc[mi][ni] = __builtin_amdgcn_mfma_f32_16x16x32_bf16(af[mi], bf[ni], acc[mi][ni], 0, 0, 0);
    }
    __syncthreads();
  }

  float* SMf = (float*)SM;                 // 64 x 132 fp32
  for (int mi = 0; mi < 4; ++mi)
    for (int ni = 0; ni < 2; ++ni) {
      int ln = wn + ni * 16 + m16;
      float bb = bias[n0 + ln];
      for (int reg = 0; reg < 4; ++reg)
        SMf[(mi * 16 + quad * 4 + reg) * 132 + ln] = acc[mi][ni][reg] + bb;
    }
  __syncthreads();
  for (int j = 0; j < 8; ++j) {
    int c = j * 256 + tid;                 // 2048 float4 chunks
    int m = c >> 5, n4 = (c & 31) * 4;
    size_t idx = (size_t)(m0 + m) * N + n0 + n4;
    float4 v = *(const float4*)&SMf[m * 132 + n4];
    float4 rr = *(const float4*)&resid[idx];
    v.x += rr.x; v.y += rr.y; v.z += rr.z; v.w += rr.w;
    *(float4*)&outf[idx] = v;
  }
}

// ---------------------------------------------------------------------------
// K3 (r4-verbatim): flash attention, 256 thr, 4 waves x 32 q-rows, single
// 32KB buffer, per-u produce/consume, raw v_exp_f32, packed cvt_pk_bf16,
// ones-column MFMA denominator, setprio, LDS-coalesced epilogue.
// ---------------------------------------------------------------------------
__global__ __launch_bounds__(256, 4) void attn_kernel(
    const unsigned short* __restrict__ qb, const unsigned short* __restrict__ kb,
    const unsigned short* __restrict__ vtb, unsigned short* __restrict__ ao) {
  const int head = blockIdx.x, qt = blockIdx.y;
  const int b = head >> 3, h = head & 7;
  const int tid = threadIdx.x;
  const int wid = tid >> 6, lane = tid & 63;
  const int quad = lane >> 4, m16 = lane & 15;
  const int sw = m16 & 7;

  __shared__ alignas(16) unsigned short SMEM[16384];   // 32 KB
  unsigned short* sK = SMEM;           // 128x64, swizzled (16 KB)
  unsigned short* sV = SMEM + 8192;    // Vt 64x128 (s permuted), swizzled (16 KB)

  const unsigned short* kbase = kb  + (size_t)head * SEQ * HDIM;
  const unsigned short* vbase = vtb + (size_t)head * HDIM * SEQ;

  short8 aq[2][2];
  for (int qblk = 0; qblk < 2; ++qblk) {
    const size_t qrow = (size_t)head * SEQ + qt * 128 + wid * 32 + qblk * 16 + m16;
    aq[qblk][0] = *(const short8*)(qb + qrow * HDIM + quad * 8);
    aq[qblk][1] = *(const short8*)(qb + qrow * HDIM + 32 + quad * 8);
  }

  const unsigned int onep = 0x3F803F80u;               // bf16(1.0) x2
  const short8 vones = __builtin_bit_cast(short8, (uint4v){onep, onep, onep, onep});

  floatx4 la[2];
  floatx4 o[2][4];
  for (int qblk = 0; qblk < 2; ++qblk) {
    la[qblk] = 0.f;
    for (int df = 0; df < 4; ++df) o[qblk][df] = 0.f;
  }

  for (int kt = 0; kt < 8; ++kt) {
    if (kt) __syncthreads();
    for (int i = 0; i < 4; ++i) {
      int c = i * 256 + tid;
      int r = c >> 3, kc = c & 7;
      load_lds16(kbase + (kt * 128 + r) * HDIM + ((kc ^ (r & 7)) << 3), &sK[c << 3]);
    }
    for (int i = 0; i < 4; ++i) {
      int c = i * 256 + tid;
      int d = c >> 4, kc = c & 15;
      load_lds16(vbase + d * SEQ + kt * 128 + ((kc ^ (d & 7)) << 3), &sV[c << 3]);
    }
    __syncthreads();

    for (int u = 0; u < 4; ++u) {
      unsigned int pw[2][4];
      for (int t = 0; t < 2; ++t) {
        const int sf = u * 2 + t;
        const int rb = (sf * 16 + m16) * 64;
        short8 k0 = *(const short8*)&sK[rb + ((quad ^ sw) << 3)];
        short8 k1 = *(const short8*)&sK[rb + (((4 + quad) ^ sw) << 3)];
        floatx4 s0 = 0.f, s1 = 0.f;
        __builtin_amdgcn_s_setprio(1);
        s0 = __builtin_amdgcn_mfma_f32_16x16x32_bf16(k0, aq[0][0], s0, 0, 0, 0);
        s0 = __builtin_amdgcn_mfma_f32_16x16x32_bf16(k1, aq[0][1], s0, 0, 0, 0);
        s1 = __builtin_amdgcn_mfma_f32_16x16x32_bf16(k0, aq[1][0], s1, 0, 0, 0);
        s1 = __builtin_amdgcn_mfma_f32_16x16x32_bf16(k1, aq[1][1], s1, 0, 0, 0);
        __builtin_amdgcn_s_setprio(0);
        pw[0][t * 2 + 0] = cvt_pk_bf16(EXP2F(s0[0]), EXP2F(s0[1]));
        pw[0][t * 2 + 1] = cvt_pk_bf16(EXP2F(s0[2]), EXP2F(s0[3]));
        pw[1][t * 2 + 0] = cvt_pk_bf16(EXP2F(s1[0]), EXP2F(s1[1]));
        pw[1][t * 2 + 1] = cvt_pk_bf16(EXP2F(s1[2]), EXP2F(s1[3]));
      }
      const short8 pf0 = __builtin_bit_cast(
          short8, (uint4v){pw[0][0], pw[0][1], pw[0][2], pw[0][3]});
      const short8 pf1 = __builtin_bit_cast(
          short8, (uint4v){pw[1][0], pw[1][1], pw[1][2], pw[1][3]});
      const int chunk = ((u * 4 + quad) ^ sw) << 3;
      __builtin_amdgcn_s_setprio(1);
      for (int df = 0; df < 4; ++df) {
        short8 bv = *(const short8*)&sV[(df * 16 + m16) * 128 + chunk];
        o[0][df] = __builtin_amdgcn_mfma_f32_16x16x32_bf16(pf0, bv, o[0][df], 0, 0, 0);
        o[1][df] = __builtin_amdgcn_mfma_f32_16x16x32_bf16(pf1, bv, o[1][df], 0, 0, 0);
      }
      la[0] = __builtin_amdgcn_mfma_f32_16x16x32_bf16(pf0, vones, la[0], 0, 0, 0);
      la[1] = __builtin_amdgcn_mfma_f32_16x16x32_bf16(pf1, vones, la[1], 0, 0, 0);
      __builtin_amdgcn_s_setprio(0);
    }
  }
  __syncthreads();

  float* Sc = (float*)SMEM;
  for (int qblk = 0; qblk < 2; ++qblk) {
    floatx4 lr;
    for (int r = 0; r < 4; ++r) lr[r] = 1.0f / la[qblk][r];
    const int row0 = wid * 32 + qblk * 16 + quad * 4;
    for (int df = 0; df < 4; ++df) {
      const int col = df * 16 + m16;
      Sc[(row0 + 0) * 64 + col] = o[qblk][df][0] * lr[0];
      Sc[(row0 + 1) * 64 + col] = o[qblk][df][1] * lr[1];
      Sc[(row0 + 2) * 64 + col] = o[qblk][df][2] * lr[2];
      Sc[(row0 + 3) * 64 + col] = o[qblk][df][3] * lr[3];
    }
  }
  __syncthreads();
  for (int j = 0; j < 4; ++j) {
    int c = j * 256 + tid;             // 1024 8-col chunks
    int m = c >> 3, n8 = (c & 7) * 8;
    floatx4 v0 = *(const floatx4*)&Sc[m * 64 + n8];
    floatx4 v1 = *(const floatx4*)&Sc[m * 64 + n8 + 4];
    int4 w;
    w.x = (int)cvt_pk_bf16(v0[0], v0[1]);
    w.y = (int)cvt_pk_bf16(v0[2], v0[3]);
    w.z = (int)cvt_pk_bf16(v1[0], v1[1]);
    w.w = (int)cvt_pk_bf16(v1[2], v1[3]);
    *(int4*)(ao + (size_t)(b * SEQ + qt * 128 + m) * CH + h * HDIM + n8) = w;
  }
}

// ---------------------------------------------------------------------------
extern "C" void kernel_launch(void* const* d_in, const int* in_sizes, int n_in,
                              void* d_out, int out_size, void* d_ws, size_t ws_size,
                              hipStream_t stream) {
  const float* x    = (const float*)d_in[0];
  const float* gsc  = (const float*)d_in[1];
  const float* gbs  = (const float*)d_in[2];
  const float* wqkv = (const float*)d_in[3];
  const float* bqkv = (const float*)d_in[4];
  const float* wout = (const float*)d_in[5];
  const float* bout = (const float*)d_in[6];
  float* out = (float*)d_out;

  char* ws = (char*)d_ws;
  unsigned short* xn    = (unsigned short*)(ws);                 // 8 MB (8192x512)
  unsigned short* wqkvt = (unsigned short*)(ws + 8388608);       // 1.5 MB (1536x512)
  unsigned short* woutt = (unsigned short*)(ws + 9961472);       // 0.5 MB (512x512)
  unsigned short* qb    = (unsigned short*)(ws + 10485760);      // 8 MB (64,1024,64)
  unsigned short* kb    = (unsigned short*)(ws + 18874368);      // 8 MB (64,1024,64)
  unsigned short* vtb   = (unsigned short*)(ws + 27262976);      // 8 MB (64,64,1024)
  unsigned short* ao    = (unsigned short*)(ws + 35651584);      // 8 MB (8192x512)

  prep_kernel<<<512, 1024, 0, stream>>>(wqkv, wout, x, gsc, gbs, wqkvt, woutt, xn);
  gemm_qkv_kernel<<<dim3(64, 6), 512, 0, stream>>>(xn, wqkvt, bqkv, qb, kb, vtb);
  attn_kernel<<<dim3(64, 8), 256, 0, stream>>>(qb, kb, vtb, ao);
  gemm_out_kernel<<<dim3(128, 4), 256, 0, stream>>>(ao, woutt, bout, x, out);
}